// Round 10
// baseline (523.301 us; speedup 1.0000x reference)
//
#include <hip/hip_runtime.h>
#include <cstdint>
#include <cstddef>

#define FDIM 128
#define CHUNK 4096   // edges per binning chunk
#define BSHIFT 8     // 256 nodes per bucket
#define BMASK 255
#define MAXB 512     // max buckets supported (N <= 131072)
#define EBMAX 12288  // per-bucket edge staging (avg 4096, 64-sigma headroom)

typedef unsigned short ushort_t;
typedef __attribute__((ext_vector_type(8))) short short8;   // 8 bf16 (4 VGPRs)
typedef __attribute__((ext_vector_type(4))) float floatx4;  // MFMA C/D

// bf16 helpers (bit-level, RTN-even).
__device__ inline ushort_t f2bf(float f) {
  unsigned u = __float_as_uint(f);
  u += 0x7fffu + ((u >> 16) & 1u);
  return (ushort_t)(u >> 16);
}
__device__ inline float bf2f(ushort_t h) {
  return __uint_as_float((unsigned)h << 16);
}

// ---------------- CSR build (bucketed, coalesced-write) ----------------

__global__ __launch_bounds__(256) void k_hist(const int* __restrict__ dst, int e,
                                              int nb, int* __restrict__ chunkHist) {
  __shared__ int h[MAXB];
  int c = blockIdx.x;
  int base = c * CHUNK;
  int end = min(base + CHUNK, e);
  for (int i = threadIdx.x; i < nb; i += 256) h[i] = 0;
  __syncthreads();
  for (int i = base + threadIdx.x; i < end; i += 256)
    atomicAdd(&h[dst[i] >> BSHIFT], 1);
  __syncthreads();
  for (int b = threadIdx.x; b < nb; b += 256)
    chunkHist[(size_t)c * nb + b] = h[b];
}

// Per-bucket scan over the chunk axis (one block per bucket). Bucket base is
// ATOMIC-BUMP allocated (disjoint, order-free -- CSR bucket order in memory
// is arbitrary), which kills the old k_scan2 cross-bucket prefix kernel.
__global__ __launch_bounds__(512) void k_scan1(const int* __restrict__ chunkHist,
                                               int nchunks, int nb,
                                               int* __restrict__ chunkOff,
                                               int* __restrict__ bucketTotal,
                                               int* __restrict__ bucketBase,
                                               int* __restrict__ counter) {
  __shared__ int sb[512];
  int b = blockIdx.x;
  int t = threadIdx.x;
  int base = 0;
  for (int c0 = 0; c0 < nchunks; c0 += 512) {
    int c = c0 + t;
    int v = (c < nchunks) ? chunkHist[(size_t)c * nb + b] : 0;
    int x = v;
    sb[t] = x;
    __syncthreads();
    for (int off = 1; off < 512; off <<= 1) {
      int y = (t >= off) ? sb[t - off] : 0;
      __syncthreads();
      x += y;
      sb[t] = x;
      __syncthreads();
    }
    if (c < nchunks) chunkOff[(size_t)c * nb + b] = base + x - v;  // bucket-local
    int tileTot = sb[511];
    __syncthreads();
    base += tileTot;
  }
  if (t == 0) {
    bucketTotal[b] = base;
    bucketBase[b] = atomicAdd(counter, base);
  }
}

// Counting-sort each chunk into bucket-major order; write the sorted chunk
// CONTIGUOUSLY at binned[c*CHUNK ...] (fully coalesced -- the old global
// bucket-segment scatter had ~2.4x write amplification + RFO). Also emits
// chunkLB[c][b] = within-chunk bucket offset for k_fill2's run gather.
__global__ __launch_bounds__(256) void k_bin(const int* __restrict__ src,
                                             const int* __restrict__ dst, int e, int nb,
                                             const int* __restrict__ chunkHist,
                                             int* __restrict__ chunkLB,
                                             unsigned* __restrict__ binned) {
  __shared__ unsigned sortedL[CHUNK];
  __shared__ int lbase[MAXB], lcur[MAXB];
  __shared__ int stmp[256];
  int c = blockIdx.x;
  int base = c * CHUNK;
  int end = min(base + CHUNK, e);
  for (int i = threadIdx.x; i < nb; i += 256)
    lbase[i] = chunkHist[(size_t)c * nb + i];  // temp: counts
  __syncthreads();
  int carry = 0;
  for (int i0 = 0; i0 < nb; i0 += 256) {
    int i = i0 + threadIdx.x;
    int v = (i < nb) ? lbase[i] : 0;
    int x = v;
    stmp[threadIdx.x] = x;
    __syncthreads();
    for (int off = 1; off < 256; off <<= 1) {
      int y = (threadIdx.x >= off) ? stmp[threadIdx.x - off] : 0;
      __syncthreads();
      x += y;
      stmp[threadIdx.x] = x;
      __syncthreads();
    }
    if (i < nb) lbase[i] = carry + x - v;
    int tileTot = stmp[255];
    __syncthreads();
    carry += tileTot;
  }
  for (int i = threadIdx.x; i < nb; i += 256) {
    lcur[i] = lbase[i];
    chunkLB[(size_t)c * nb + i] = lbase[i];
  }
  __syncthreads();
  for (int i = base + threadIdx.x; i < end; i += 256) {
    int d = dst[i];
    int sv = src[i];
    int b = d >> BSHIFT;
    int slot = atomicAdd(&lcur[b], 1);
    sortedL[slot] = ((unsigned)sv << BSHIFT) | (unsigned)(d & BMASK);
  }
  __syncthreads();
  for (int i = threadIdx.x; i < end - base; i += 256)
    binned[(size_t)c * CHUNK + i] = sortedL[i];  // coalesced
}

// One block per bucket: gather this bucket's runs from all chunks into LDS
// (thread-per-chunk => thousands of independent loads in flight), then
// hist/scan/scatter. Emits rowStart, deg, dis, colPair(src,0).
__global__ __launch_bounds__(256) void k_fill2(const unsigned* __restrict__ binned,
                                               const int* __restrict__ chunkHist,
                                               const int* __restrict__ chunkLB,
                                               const int* __restrict__ chunkOff,
                                               const int* __restrict__ bucketBase,
                                               const int* __restrict__ bucketTotal,
                                               int nchunks, int nb, int n,
                                               int* __restrict__ rowStart,
                                               int* __restrict__ deg,
                                               float* __restrict__ dis,
                                               int2* __restrict__ colPair) {
  __shared__ unsigned eb[EBMAX];  // 48 KB
  __shared__ int h[256], sbv[256], cur[256];
  int b = blockIdx.x;
  int t = threadIdx.x;
  int total = min(bucketTotal[b], EBMAX);
  int gbase = bucketBase[b];
  for (int c = t; c < nchunks; c += 256) {
    int cnt = chunkHist[(size_t)c * nb + b];
    if (cnt == 0) continue;
    size_t sp = (size_t)c * CHUNK + chunkLB[(size_t)c * nb + b];
    int dp = chunkOff[(size_t)c * nb + b];
    for (int i = 0; i < cnt; ++i) {
      if (dp + i < EBMAX) eb[dp + i] = binned[sp + i];
    }
  }
  __syncthreads();
  h[t] = 0;
  __syncthreads();
  for (int i = t; i < total; i += 256) atomicAdd(&h[eb[i] & BMASK], 1);
  __syncthreads();
  int v = h[t];
  int x = v;
  sbv[t] = x;
  __syncthreads();
  for (int off = 1; off < 256; off <<= 1) {
    int y = (t >= off) ? sbv[t - off] : 0;
    __syncthreads();
    x += y;
    sbv[t] = x;
    __syncthreads();
  }
  int startL = x - v;  // bucket-local exclusive
  cur[t] = startL;
  int node = (b << BSHIFT) + t;
  if (node < n) {
    rowStart[node] = gbase + startL;
    deg[node] = v;
    dis[node] = rsqrtf((float)(v + 1));  // +1 self-loop
  }
  __syncthreads();
  for (int i = t; i < total; i += 256) {
    unsigned en = eb[i];
    int slot = atomicAdd(&cur[en & BMASK], 1);
    colPair[(size_t)gbase + slot] = int2{(int)(en >> BSHIFT), 0};
  }
}

// Fill colPair[e].y = dis[src] (src random but dis is 400 KB, L2-resident).
__global__ __launch_bounds__(256) void k_edgew(int2* __restrict__ colPair, int e,
                                               const float* __restrict__ dis) {
  int i = blockIdx.x * 256 + threadIdx.x;
  if (i < e) {
    int2 p = colPair[i];
    p.y = __float_as_int(dis[p.x]);
    colPair[i] = p;
  }
}

// ---------------- W prep: fp32 -> bf16, swizzled into B-fragment order ----
// B frag slot (ct, n=lane&15) holds TRUE column (lane&15)*8 + ct, so the C
// epilogue's 8 ct-values per lane are 8 consecutive output columns -> one
// 16 B store per row.
__global__ __launch_bounds__(256) void k_prepw(const float* __restrict__ W1,
                                               const float* __restrict__ W2,
                                               const float* __restrict__ W3,
                                               ushort_t* __restrict__ out) {
  int b = blockIdx.x;
  const float* W = (b == 0) ? W1 : (b == 1) ? W2 : W3;
  ushort_t* o = out + (size_t)b * 16384;
  for (int idx = threadIdx.x; idx < 16384; idx += 256) {
    int j = idx & 7;
    int lane = (idx >> 3) & 63;
    int ct = (idx >> 9) & 7;
    int kc = idx >> 12;
    int k = kc * 32 + (lane >> 4) * 8 + j;
    int col = (lane & 15) * 8 + ct;  // column re-map for coalesced C-stores
    o[idx] = f2bf(W[k * FDIM + col]);
  }
}

// ---------------- MFMA matmul (row-major H) ----------
template <int INBF>
__global__ __launch_bounds__(256) void k_mm(const void* __restrict__ Ain,
                                            const ushort_t* __restrict__ Wsw,
                                            ushort_t* __restrict__ O, int n) {
  __shared__ ushort_t Bs[16384];  // 32 KB
  int tid = threadIdx.x;
  for (int q = tid; q < 2048; q += 256)
    ((uint4*)Bs)[q] = ((const uint4*)Wsw)[q];
  __syncthreads();

  int w = tid >> 6;
  int lane = tid & 63;
  int quad = lane >> 4;
  int l15 = lane & 15;
  int rb = blockIdx.x * 128 + w * 32;
  const float* Af = (const float*)Ain;
  const ushort_t* Ab = (const ushort_t*)Ain;

  int row0 = rb + l15;
  int row1 = rb + 16 + l15;
  bool v0 = row0 < n, v1 = row1 < n;

  floatx4 acc[2][8];
#pragma unroll
  for (int rt = 0; rt < 2; ++rt)
#pragma unroll
    for (int ct = 0; ct < 8; ++ct) acc[rt][ct] = floatx4{0.f, 0.f, 0.f, 0.f};

#pragma unroll
  for (int kc = 0; kc < 4; ++kc) {
    int k0 = kc * 32 + quad * 8;
    short8 a0 = short8{0, 0, 0, 0, 0, 0, 0, 0};
    short8 a1 = short8{0, 0, 0, 0, 0, 0, 0, 0};
    if (INBF) {
      if (v0) a0 = *(const short8*)&Ab[(size_t)row0 * FDIM + k0];
      if (v1) a1 = *(const short8*)&Ab[(size_t)row1 * FDIM + k0];
    } else {
      if (v0) {
        float4 f0 = *(const float4*)&Af[(size_t)row0 * FDIM + k0];
        float4 f1 = *(const float4*)&Af[(size_t)row0 * FDIM + k0 + 4];
        a0 = short8{(short)f2bf(f0.x), (short)f2bf(f0.y), (short)f2bf(f0.z),
                    (short)f2bf(f0.w), (short)f2bf(f1.x), (short)f2bf(f1.y),
                    (short)f2bf(f1.z), (short)f2bf(f1.w)};
      }
      if (v1) {
        float4 f0 = *(const float4*)&Af[(size_t)row1 * FDIM + k0];
        float4 f1 = *(const float4*)&Af[(size_t)row1 * FDIM + k0 + 4];
        a1 = short8{(short)f2bf(f0.x), (short)f2bf(f0.y), (short)f2bf(f0.z),
                    (short)f2bf(f0.w), (short)f2bf(f1.x), (short)f2bf(f1.y),
                    (short)f2bf(f1.z), (short)f2bf(f1.w)};
      }
    }
#pragma unroll
    for (int ct = 0; ct < 8; ++ct) {
      short8 bf = *(const short8*)&Bs[((kc * 8 + ct) * 64 + lane) * 8];
      acc[0][ct] = __builtin_amdgcn_mfma_f32_16x16x32_bf16(a0, bf, acc[0][ct], 0, 0, 0);
      acc[1][ct] = __builtin_amdgcn_mfma_f32_16x16x32_bf16(a1, bf, acc[1][ct], 0, 0, 0);
    }
  }

#pragma unroll
  for (int rt = 0; rt < 2; ++rt) {
#pragma unroll
    for (int i = 0; i < 4; ++i) {
      int row = rb + rt * 16 + quad * 4 + i;
      if (row < n) {
        uint4 pk;
        pk.x = (unsigned)f2bf(acc[rt][0][i]) | ((unsigned)f2bf(acc[rt][1][i]) << 16);
        pk.y = (unsigned)f2bf(acc[rt][2][i]) | ((unsigned)f2bf(acc[rt][3][i]) << 16);
        pk.z = (unsigned)f2bf(acc[rt][4][i]) | ((unsigned)f2bf(acc[rt][5][i]) << 16);
        pk.w = (unsigned)f2bf(acc[rt][6][i]) | ((unsigned)f2bf(acc[rt][7][i]) << 16);
        *(uint4*)&O[(size_t)row * FDIM + l15 * 8] = pk;
      }
    }
  }
}

// ---------------- aggregation (pull) + bias + ReLU, row-major bf16 --------
// 2 nodes per wave: 32 lanes x uint2 (8 B) = 256 B row. colPair loads and
// Hout stores are NONTEMPORAL (streaming; keep per-XCD L2 for H gather
// lines). unroll 8 -> more outstanding 256 B gathers.
__global__ __launch_bounds__(256) void k_agg(const ushort_t* __restrict__ Hin,
                                             ushort_t* __restrict__ Hout,
                                             const int* __restrict__ rowStart,
                                             const int* __restrict__ degE,
                                             const int2* __restrict__ colPair,
                                             const float* __restrict__ dis,
                                             const float* __restrict__ bias, int n) {
  int node = blockIdx.x * 8 + (threadIdx.x >> 5);
  int lane = threadIdx.x & 31;  // uint2 index within the 256 B row
  if (node >= n) return;
  const uint2* hin = (const uint2*)Hin;  // row stride 32 uint2
  float di = dis[node];
  uint2 su = hin[(size_t)node * 32 + lane];
  float ws = di * di;
  float a0 = ws * __uint_as_float(su.x << 16);
  float a1 = ws * __uint_as_float(su.x & 0xffff0000u);
  float a2 = ws * __uint_as_float(su.y << 16);
  float a3 = ws * __uint_as_float(su.y & 0xffff0000u);
  int s0 = rowStart[node], cnt = degE[node];
  const long long* cp = (const long long*)(colPair + s0);
#pragma unroll 8
  for (int j = 0; j < cnt; ++j) {
    long long pv = __builtin_nontemporal_load(cp + j);
    int sidx = (int)(unsigned)(pv & 0xffffffffLL);
    float w = di * __int_as_float((int)(pv >> 32));
    uint2 u = hin[(size_t)sidx * 32 + lane];
    a0 += w * __uint_as_float(u.x << 16);
    a1 += w * __uint_as_float(u.x & 0xffff0000u);
    a2 += w * __uint_as_float(u.y << 16);
    a3 += w * __uint_as_float(u.y & 0xffff0000u);
  }
  float4 b = ((const float4*)bias)[lane];
  a0 = fmaxf(a0 + b.x, 0.f);
  a1 = fmaxf(a1 + b.y, 0.f);
  a2 = fmaxf(a2 + b.z, 0.f);
  a3 = fmaxf(a3 + b.w, 0.f);
  unsigned long long ov =
      (unsigned long long)((unsigned)f2bf(a0) | ((unsigned)f2bf(a1) << 16)) |
      ((unsigned long long)((unsigned)f2bf(a2) | ((unsigned)f2bf(a3) << 16)) << 32);
  __builtin_nontemporal_store(
      ov, (unsigned long long*)((uint2*)Hout + (size_t)node * 32 + lane));
}

// ---------------- pooling (self-contained binary search) ----------------

__device__ inline int lower_bound_batch(const int* __restrict__ batch, int n, int g) {
  int lo = 0, hi = n;
  while (lo < hi) {
    int mid = (lo + hi) >> 1;
    if (batch[mid] < g) lo = mid + 1;
    else hi = mid;
  }
  return lo;
}

__global__ __launch_bounds__(128) void k_pool(const ushort_t* __restrict__ H,
                                              const int* __restrict__ batch, int n,
                                              float* __restrict__ pooled, int g_count) {
  __shared__ int se[2];
  int g = blockIdx.x >> 4;
  int c = blockIdx.x & 15;
  if (threadIdx.x < 2)
    se[threadIdx.x] = lower_bound_batch(batch, n, g + (int)threadIdx.x);
  __syncthreads();
  int s = se[0], e = se[1];
  int len = e - s;
  int chunk = (len + 15) >> 4;
  int ns = s + c * chunk;
  int ne = min(ns + chunk, e);
  float acc = 0.f;
  for (int i = ns; i < ne; ++i) acc += bf2f(H[(size_t)i * FDIM + threadIdx.x]);
  atomicAdd(&pooled[g * FDIM + threadIdx.x], acc);
}

__global__ __launch_bounds__(192) void k_final(const float* __restrict__ pooled,
                                               const int* __restrict__ batch, int n,
                                               const float* __restrict__ Wc,
                                               const float* __restrict__ bc,
                                               float* __restrict__ out, int g_count) {
  int t = threadIdx.x;
  if (t >= g_count * 3) return;
  int g = t / 3, c = t % 3;
  int cnt = lower_bound_batch(batch, n, g + 1) - lower_bound_batch(batch, n, g);
  float inv = 1.0f / (float)max(cnt, 1);
  float acc = bc[c];
#pragma unroll 8
  for (int k = 0; k < FDIM; ++k) acc += pooled[g * FDIM + k] * inv * Wc[k * 3 + c];
  out[g * 3 + c] = acc;
}

// ---------------- host ----------------

extern "C" void kernel_launch(void* const* d_in, const int* in_sizes, int n_in,
                              void* d_out, int out_size, void* d_ws, size_t ws_size,
                              hipStream_t stream) {
  const float* x = (const float*)d_in[0];
  const int* edge = (const int*)d_in[1];
  const int* batch = (const int*)d_in[2];
  const float* W1 = (const float*)d_in[3];
  const float* b1 = (const float*)d_in[4];
  const float* W2 = (const float*)d_in[5];
  const float* b2 = (const float*)d_in[6];
  const float* W3 = (const float*)d_in[7];
  const float* b3 = (const float*)d_in[8];
  const float* Wc = (const float*)d_in[9];
  const float* bc = (const float*)d_in[10];
  float* out = (float*)d_out;

  const int N = in_sizes[0] / FDIM;
  const int E = in_sizes[1] / 2;
  const int G = out_size / 3;
  const int* src = edge;
  const int* dst = edge + E;

  const int NCH = (E + CHUNK - 1) / CHUNK;
  const int NB = (N + (1 << BSHIFT) - 1) >> BSHIFT;

  char* ws = (char*)d_ws;
  size_t off = 0;
  auto carve = [&](size_t bytes) -> void* {
    void* p = ws + off;
    off = (off + bytes + 255) & ~(size_t)255;
    return p;
  };
  ushort_t* h0 = (ushort_t*)carve((size_t)N * FDIM * 2);  // row-major bf16
  ushort_t* h1 = (ushort_t*)carve((size_t)N * FDIM * 2);
  int2* colPair = (int2*)carve((size_t)E * 8);
  unsigned* binned = (unsigned*)carve((size_t)NCH * CHUNK * 4);
  int* chunkHist = (int*)carve((size_t)NCH * NB * 4);
  int* chunkOff = (int*)carve((size_t)NCH * NB * 4);
  int* chunkLB = (int*)carve((size_t)NCH * NB * 4);
  int* bucketTotal = (int*)carve((size_t)NB * 4);
  int* bucketBase = (int*)carve((size_t)NB * 4);
  int* counter = (int*)carve(256);
  int* rowStart = (int*)carve((size_t)N * 4);
  int* deg = (int*)carve((size_t)N * 4);
  float* dis = (float*)carve((size_t)N * 4);
  float* pooled = (float*)carve((size_t)G * FDIM * 4);
  ushort_t* wsw = (ushort_t*)carve((size_t)3 * 16384 * 2);  // swizzled bf16 W
  (void)n_in;
  (void)ws_size;

  hipMemsetAsync(pooled, 0, (size_t)G * FDIM * 4, stream);
  hipMemsetAsync(counter, 0, 4, stream);

  k_hist<<<NCH, 256, 0, stream>>>(dst, E, NB, chunkHist);
  k_scan1<<<NB, 512, 0, stream>>>(chunkHist, NCH, NB, chunkOff, bucketTotal,
                                  bucketBase, counter);
  k_bin<<<NCH, 256, 0, stream>>>(src, dst, E, NB, chunkHist, chunkLB, binned);
  k_fill2<<<NB, 256, 0, stream>>>(binned, chunkHist, chunkLB, chunkOff, bucketBase,
                                  bucketTotal, NCH, NB, N, rowStart, deg, dis,
                                  colPair);
  k_edgew<<<(E + 255) / 256, 256, 0, stream>>>(colPair, E, dis);
  k_prepw<<<3, 256, 0, stream>>>(W1, W2, W3, wsw);

  int mmb = (N + 127) / 128;
  int aggb = (N + 7) / 8;
  k_mm<0><<<mmb, 256, 0, stream>>>(x, wsw, h0, N);
  k_agg<<<aggb, 256, 0, stream>>>(h0, h1, rowStart, deg, colPair, dis, b1, N);
  k_mm<1><<<mmb, 256, 0, stream>>>(h1, wsw + 16384, h0, N);
  k_agg<<<aggb, 256, 0, stream>>>(h0, h1, rowStart, deg, colPair, dis, b2, N);
  k_mm<1><<<mmb, 256, 0, stream>>>(h1, wsw + 32768, h0, N);
  k_agg<<<aggb, 256, 0, stream>>>(h0, h1, rowStart, deg, colPair, dis, b3, N);

  k_pool<<<G * 16, 128, 0, stream>>>(h1, batch, N, pooled, G);
  k_final<<<1, 192, 0, stream>>>(pooled, batch, N, Wc, bc, out, G);
}

// Round 11
// 431.618 us; speedup vs baseline: 1.2124x; 1.2124x over previous
//
#include <hip/hip_runtime.h>
#include <cstdint>
#include <cstddef>

#define FDIM 128
#define CHUNK 4096   // edges per binning chunk
#define BSHIFT 8     // 256 nodes per bucket
#define BMASK 255
#define MAXB 512     // max buckets supported (N <= 131072)

typedef unsigned short ushort_t;
typedef __attribute__((ext_vector_type(8))) short short8;   // 8 bf16 (4 VGPRs)
typedef __attribute__((ext_vector_type(4))) float floatx4;  // MFMA C/D

// bf16 helpers (bit-level, RTN-even).
__device__ inline ushort_t f2bf(float f) {
  unsigned u = __float_as_uint(f);
  u += 0x7fffu + ((u >> 16) & 1u);
  return (ushort_t)(u >> 16);
}
__device__ inline float bf2f(ushort_t h) {
  return __uint_as_float((unsigned)h << 16);
}

// ---------------- CSR build (bucketed, round-9 proven) ----------------
// k_histw: blocks [0,NCH) = per-chunk dst-bucket histogram; blocks
// [NCH,NCH+3) = W prep (independent work fused to save a launch).
__global__ __launch_bounds__(256) void k_histw(const int* __restrict__ dst, int e,
                                               int nb, int* __restrict__ chunkHist,
                                               int nch,
                                               const float* __restrict__ W1,
                                               const float* __restrict__ W2,
                                               const float* __restrict__ W3,
                                               ushort_t* __restrict__ wsw) {
  if (blockIdx.x >= (unsigned)nch) {
    // ---- W prep: fp32 -> bf16, swizzled into B-fragment order. B frag slot
    // (ct, n=lane&15) holds TRUE column (lane&15)*8+ct so the C epilogue's 8
    // ct-values per lane are consecutive columns -> one 16 B store per row.
    int b = blockIdx.x - nch;
    const float* W = (b == 0) ? W1 : (b == 1) ? W2 : W3;
    ushort_t* o = wsw + (size_t)b * 16384;
    for (int idx = threadIdx.x; idx < 16384; idx += 256) {
      int j = idx & 7;
      int lane = (idx >> 3) & 63;
      int ct = (idx >> 9) & 7;
      int kc = idx >> 12;
      int k = kc * 32 + (lane >> 4) * 8 + j;
      int col = (lane & 15) * 8 + ct;
      o[idx] = f2bf(W[k * FDIM + col]);
    }
    return;
  }
  __shared__ int h[MAXB];
  int c = blockIdx.x;
  int base = c * CHUNK;
  int end = min(base + CHUNK, e);
  for (int i = threadIdx.x; i < nb; i += 256) h[i] = 0;
  __syncthreads();
  for (int i = base + threadIdx.x; i < end; i += 256)
    atomicAdd(&h[dst[i] >> BSHIFT], 1);
  __syncthreads();
  for (int b = threadIdx.x; b < nb; b += 256)
    chunkHist[(size_t)c * nb + b] = h[b];
}

// Per-bucket scan over the chunk axis (one block per bucket).
__global__ __launch_bounds__(512) void k_scan1(const int* __restrict__ chunkHist,
                                               int nchunks, int nb,
                                               int* __restrict__ chunkOff,
                                               int* __restrict__ bucketTotal) {
  __shared__ int sb[512];
  int b = blockIdx.x;
  int t = threadIdx.x;
  int base = 0;
  for (int c0 = 0; c0 < nchunks; c0 += 512) {
    int c = c0 + t;
    int v = (c < nchunks) ? chunkHist[(size_t)c * nb + b] : 0;
    int x = v;
    sb[t] = x;
    __syncthreads();
    for (int off = 1; off < 512; off <<= 1) {
      int y = (t >= off) ? sb[t - off] : 0;
      __syncthreads();
      x += y;
      sb[t] = x;
      __syncthreads();
    }
    if (c < nchunks) chunkOff[(size_t)c * nb + b] = base + x - v;
    int tileTot = sb[511];
    __syncthreads();
    base += tileTot;
  }
  if (t == 0) bucketTotal[b] = base;
}

__global__ __launch_bounds__(512) void k_scan2(const int* __restrict__ bucketTotal,
                                               int nb, int e,
                                               int* __restrict__ bucketBase) {
  __shared__ int sb[512];
  int t = threadIdx.x;
  int v = (t < nb) ? bucketTotal[t] : 0;
  int x = v;
  sb[t] = x;
  __syncthreads();
  for (int off = 1; off < 512; off <<= 1) {
    int y = (t >= off) ? sb[t - off] : 0;
    __syncthreads();
    x += y;
    sb[t] = x;
    __syncthreads();
  }
  if (t < nb) bucketBase[t] = x - v;
  if (t == 0) bucketBase[nb] = e;
}

__global__ __launch_bounds__(256) void k_bin(const int* __restrict__ src,
                                             const int* __restrict__ dst, int e, int nb,
                                             const int* __restrict__ chunkHist,
                                             const int* __restrict__ chunkOff,
                                             const int* __restrict__ bucketBase,
                                             unsigned* __restrict__ binned) {
  __shared__ unsigned sortedL[CHUNK];
  __shared__ int gtarget[CHUNK];
  __shared__ int lbase[MAXB], lcur[MAXB], gbase[MAXB];
  __shared__ int stmp[256];
  int c = blockIdx.x;
  int base = c * CHUNK;
  int end = min(base + CHUNK, e);
  for (int i = threadIdx.x; i < nb; i += 256) {
    lbase[i] = chunkHist[(size_t)c * nb + i];  // temp: counts
    gbase[i] = bucketBase[i] + chunkOff[(size_t)c * nb + i];
  }
  __syncthreads();
  int carry = 0;
  for (int i0 = 0; i0 < nb; i0 += 256) {
    int i = i0 + threadIdx.x;
    int v = (i < nb) ? lbase[i] : 0;
    int x = v;
    stmp[threadIdx.x] = x;
    __syncthreads();
    for (int off = 1; off < 256; off <<= 1) {
      int y = (threadIdx.x >= off) ? stmp[threadIdx.x - off] : 0;
      __syncthreads();
      x += y;
      stmp[threadIdx.x] = x;
      __syncthreads();
    }
    if (i < nb) lbase[i] = carry + x - v;
    int tileTot = stmp[255];
    __syncthreads();
    carry += tileTot;
  }
  for (int i = threadIdx.x; i < nb; i += 256) lcur[i] = lbase[i];
  __syncthreads();
  for (int i = base + threadIdx.x; i < end; i += 256) {
    int d = dst[i];
    int sv = src[i];
    int b = d >> BSHIFT;
    int slot = atomicAdd(&lcur[b], 1);
    sortedL[slot] = ((unsigned)sv << BSHIFT) | (unsigned)(d & BMASK);
    gtarget[slot] = gbase[b] + (slot - lbase[b]);
  }
  __syncthreads();
  for (int i = threadIdx.x; i < end - base; i += 256)
    binned[gtarget[i]] = sortedL[i];
}

__global__ __launch_bounds__(256) void k_fill2(const unsigned* __restrict__ binned,
                                               const int* __restrict__ bucketBase, int n,
                                               int* __restrict__ rowStart,
                                               int* __restrict__ deg,
                                               float* __restrict__ dis,
                                               int2* __restrict__ colPair) {
  __shared__ int h[256], sb[256], cur[256];
  int b = blockIdx.x;
  int s0 = bucketBase[b], s1 = bucketBase[b + 1];
  int nodeBase = b << BSHIFT;
  int t = threadIdx.x;
  h[t] = 0;
  __syncthreads();
  for (int i = s0 + t; i < s1; i += 256) atomicAdd(&h[binned[i] & BMASK], 1);
  __syncthreads();
  int v = h[t];
  int x = v;
  sb[t] = x;
  __syncthreads();
  for (int off = 1; off < 256; off <<= 1) {
    int y = (t >= off) ? sb[t - off] : 0;
    __syncthreads();
    x += y;
    sb[t] = x;
    __syncthreads();
  }
  int start = s0 + x - v;
  cur[t] = start;
  int node = nodeBase + t;
  if (node < n) {
    rowStart[node] = start;
    deg[node] = v;
    dis[node] = rsqrtf((float)(v + 1));  // +1 self-loop
  }
  __syncthreads();
  for (int i = s0 + t; i < s1; i += 256) {
    unsigned en = binned[i];
    int slot = atomicAdd(&cur[en & BMASK], 1);
    colPair[slot] = int2{(int)(en >> BSHIFT), 0};
  }
}

// ---------------- MFMA matmul (row-major H) ----------
// mm body for blocks [0,mmb); blocks [mmb, mmb+extra) run the edgew loop
// (colPair[i].y = dis[src]; dis is 400 KB L2-resident) -- fused to save a
// launch and overlap its streaming with mm's MFMA work. EDGW=1 only for the
// first (INBF=0) instantiation.
template <int INBF, int EDGW>
__global__ __launch_bounds__(256) void k_mm(const void* __restrict__ Ain,
                                            const ushort_t* __restrict__ Wsw,
                                            ushort_t* __restrict__ O, int n, int mmb,
                                            int2* __restrict__ colPair, int e,
                                            const float* __restrict__ dis) {
  if (EDGW && blockIdx.x >= (unsigned)mmb) {
    int base = (blockIdx.x - mmb) * 2048 + threadIdx.x;
    for (int k = 0; k < 8; ++k) {
      int i = base + k * 256;
      if (i < e) {
        int2 p = colPair[i];
        p.y = __float_as_int(dis[p.x]);
        colPair[i] = p;
      }
    }
    return;
  }
  __shared__ ushort_t Bs[16384];  // 32 KB
  int tid = threadIdx.x;
  for (int q = tid; q < 2048; q += 256)
    ((uint4*)Bs)[q] = ((const uint4*)Wsw)[q];
  __syncthreads();

  int w = tid >> 6;
  int lane = tid & 63;
  int quad = lane >> 4;
  int l15 = lane & 15;
  int rb = blockIdx.x * 128 + w * 32;
  const float* Af = (const float*)Ain;
  const ushort_t* Ab = (const ushort_t*)Ain;

  int row0 = rb + l15;
  int row1 = rb + 16 + l15;
  bool v0 = row0 < n, v1 = row1 < n;

  floatx4 acc[2][8];
#pragma unroll
  for (int rt = 0; rt < 2; ++rt)
#pragma unroll
    for (int ct = 0; ct < 8; ++ct) acc[rt][ct] = floatx4{0.f, 0.f, 0.f, 0.f};

#pragma unroll
  for (int kc = 0; kc < 4; ++kc) {
    int k0 = kc * 32 + quad * 8;
    short8 a0 = short8{0, 0, 0, 0, 0, 0, 0, 0};
    short8 a1 = short8{0, 0, 0, 0, 0, 0, 0, 0};
    if (INBF) {
      if (v0) a0 = *(const short8*)&Ab[(size_t)row0 * FDIM + k0];
      if (v1) a1 = *(const short8*)&Ab[(size_t)row1 * FDIM + k0];
    } else {
      if (v0) {
        float4 f0 = *(const float4*)&Af[(size_t)row0 * FDIM + k0];
        float4 f1 = *(const float4*)&Af[(size_t)row0 * FDIM + k0 + 4];
        a0 = short8{(short)f2bf(f0.x), (short)f2bf(f0.y), (short)f2bf(f0.z),
                    (short)f2bf(f0.w), (short)f2bf(f1.x), (short)f2bf(f1.y),
                    (short)f2bf(f1.z), (short)f2bf(f1.w)};
      }
      if (v1) {
        float4 f0 = *(const float4*)&Af[(size_t)row1 * FDIM + k0];
        float4 f1 = *(const float4*)&Af[(size_t)row1 * FDIM + k0 + 4];
        a1 = short8{(short)f2bf(f0.x), (short)f2bf(f0.y), (short)f2bf(f0.z),
                    (short)f2bf(f0.w), (short)f2bf(f1.x), (short)f2bf(f1.y),
                    (short)f2bf(f1.z), (short)f2bf(f1.w)};
      }
    }
#pragma unroll
    for (int ct = 0; ct < 8; ++ct) {
      short8 bf = *(const short8*)&Bs[((kc * 8 + ct) * 64 + lane) * 8];
      acc[0][ct] = __builtin_amdgcn_mfma_f32_16x16x32_bf16(a0, bf, acc[0][ct], 0, 0, 0);
      acc[1][ct] = __builtin_amdgcn_mfma_f32_16x16x32_bf16(a1, bf, acc[1][ct], 0, 0, 0);
    }
  }

  // acc[rt][ct][i] -> O[row][l15*8 + ct]: one uint4 store per row.
#pragma unroll
  for (int rt = 0; rt < 2; ++rt) {
#pragma unroll
    for (int i = 0; i < 4; ++i) {
      int row = rb + rt * 16 + quad * 4 + i;
      if (row < n) {
        uint4 pk;
        pk.x = (unsigned)f2bf(acc[rt][0][i]) | ((unsigned)f2bf(acc[rt][1][i]) << 16);
        pk.y = (unsigned)f2bf(acc[rt][2][i]) | ((unsigned)f2bf(acc[rt][3][i]) << 16);
        pk.z = (unsigned)f2bf(acc[rt][4][i]) | ((unsigned)f2bf(acc[rt][5][i]) << 16);
        pk.w = (unsigned)f2bf(acc[rt][6][i]) | ((unsigned)f2bf(acc[rt][7][i]) << 16);
        *(uint4*)&O[(size_t)row * FDIM + l15 * 8] = pk;
      }
    }
  }
}

// ---------------- aggregation (pull) + bias + ReLU (round-9 proven) -------
// 2 nodes per wave: 32 lanes x uint2 (8 B) = 256 B row; colPair = (src,
// dis[src]); normal cached loads (round-10's nontemporal variant REGRESSED:
// +18 MB FETCH, 66->83 us -- edge stream wants L2).
__global__ __launch_bounds__(256) void k_agg(const ushort_t* __restrict__ Hin,
                                             ushort_t* __restrict__ Hout,
                                             const int* __restrict__ rowStart,
                                             const int* __restrict__ degE,
                                             const int2* __restrict__ colPair,
                                             const float* __restrict__ dis,
                                             const float* __restrict__ bias, int n) {
  int node = blockIdx.x * 8 + (threadIdx.x >> 5);
  int lane = threadIdx.x & 31;  // uint2 index within the 256 B row
  if (node >= n) return;
  const uint2* hin = (const uint2*)Hin;  // row stride 32 uint2
  float di = dis[node];
  uint2 su = hin[(size_t)node * 32 + lane];
  float ws = di * di;
  float a0 = ws * __uint_as_float(su.x << 16);
  float a1 = ws * __uint_as_float(su.x & 0xffff0000u);
  float a2 = ws * __uint_as_float(su.y << 16);
  float a3 = ws * __uint_as_float(su.y & 0xffff0000u);
  int s0 = rowStart[node], cnt = degE[node];
#pragma unroll 4
  for (int j = 0; j < cnt; ++j) {
    int2 p = colPair[s0 + j];
    float w = di * __int_as_float(p.y);
    uint2 u = hin[(size_t)p.x * 32 + lane];
    a0 += w * __uint_as_float(u.x << 16);
    a1 += w * __uint_as_float(u.x & 0xffff0000u);
    a2 += w * __uint_as_float(u.y << 16);
    a3 += w * __uint_as_float(u.y & 0xffff0000u);
  }
  float4 b = ((const float4*)bias)[lane];
  a0 = fmaxf(a0 + b.x, 0.f);
  a1 = fmaxf(a1 + b.y, 0.f);
  a2 = fmaxf(a2 + b.z, 0.f);
  a3 = fmaxf(a3 + b.w, 0.f);
  uint2 o;
  o.x = (unsigned)f2bf(a0) | ((unsigned)f2bf(a1) << 16);
  o.y = (unsigned)f2bf(a2) | ((unsigned)f2bf(a3) << 16);
  ((uint2*)Hout)[(size_t)node * 32 + lane] = o;
}

// ---------------- pooling ----------------

__global__ __launch_bounds__(128) void k_gstart(const int* __restrict__ batch, int n,
                                                int g_count, int* __restrict__ gstart) {
  int g = threadIdx.x;
  if (g > g_count) return;
  int lo = 0, hi = n;
  while (lo < hi) {
    int mid = (lo + hi) >> 1;
    if (batch[mid] < g) lo = mid + 1;
    else hi = mid;
  }
  gstart[g] = lo;
}

__global__ __launch_bounds__(128) void k_pool(const ushort_t* __restrict__ H,
                                              const int* __restrict__ gstart,
                                              float* __restrict__ pooled, int g_count) {
  int g = blockIdx.x >> 4;
  int c = blockIdx.x & 15;
  int s = gstart[g], e = gstart[g + 1];
  int len = e - s;
  int chunk = (len + 15) >> 4;
  int ns = s + c * chunk;
  int ne = min(ns + chunk, e);
  float acc = 0.f;
  for (int i = ns; i < ne; ++i) acc += bf2f(H[(size_t)i * FDIM + threadIdx.x]);
  atomicAdd(&pooled[g * FDIM + threadIdx.x], acc);
}

__global__ __launch_bounds__(192) void k_final(const float* __restrict__ pooled,
                                               const int* __restrict__ gstart,
                                               const float* __restrict__ Wc,
                                               const float* __restrict__ bc,
                                               float* __restrict__ out, int g_count) {
  int t = threadIdx.x;
  if (t >= g_count * 3) return;
  int g = t / 3, c = t % 3;
  int cnt = gstart[g + 1] - gstart[g];
  float inv = 1.0f / (float)max(cnt, 1);
  float acc = bc[c];
#pragma unroll 8
  for (int k = 0; k < FDIM; ++k) acc += pooled[g * FDIM + k] * inv * Wc[k * 3 + c];
  out[g * 3 + c] = acc;
}

// ---------------- host ----------------

extern "C" void kernel_launch(void* const* d_in, const int* in_sizes, int n_in,
                              void* d_out, int out_size, void* d_ws, size_t ws_size,
                              hipStream_t stream) {
  const float* x = (const float*)d_in[0];
  const int* edge = (const int*)d_in[1];
  const int* batch = (const int*)d_in[2];
  const float* W1 = (const float*)d_in[3];
  const float* b1 = (const float*)d_in[4];
  const float* W2 = (const float*)d_in[5];
  const float* b2 = (const float*)d_in[6];
  const float* W3 = (const float*)d_in[7];
  const float* b3 = (const float*)d_in[8];
  const float* Wc = (const float*)d_in[9];
  const float* bc = (const float*)d_in[10];
  float* out = (float*)d_out;

  const int N = in_sizes[0] / FDIM;
  const int E = in_sizes[1] / 2;
  const int G = out_size / 3;
  const int* src = edge;
  const int* dst = edge + E;

  const int NCH = (E + CHUNK - 1) / CHUNK;
  const int NB = (N + (1 << BSHIFT) - 1) >> BSHIFT;

  char* ws = (char*)d_ws;
  size_t off = 0;
  auto carve = [&](size_t bytes) -> void* {
    void* p = ws + off;
    off = (off + bytes + 255) & ~(size_t)255;
    return p;
  };
  ushort_t* h0 = (ushort_t*)carve((size_t)N * FDIM * 2);  // row-major bf16
  ushort_t* h1 = (ushort_t*)carve((size_t)N * FDIM * 2);
  int2* colPair = (int2*)carve((size_t)E * 8);
  unsigned* binned = (unsigned*)carve((size_t)E * 4);
  int* chunkHist = (int*)carve((size_t)NCH * NB * 4);
  int* chunkOff = (int*)carve((size_t)NCH * NB * 4);
  int* bucketTotal = (int*)carve((size_t)NB * 4);
  int* bucketBase = (int*)carve((size_t)(NB + 1) * 4);
  int* rowStart = (int*)carve((size_t)N * 4);
  int* deg = (int*)carve((size_t)N * 4);
  float* dis = (float*)carve((size_t)N * 4);
  int* gstart = (int*)carve((size_t)(G + 1) * 4);
  float* pooled = (float*)carve((size_t)G * FDIM * 4);
  ushort_t* wsw = (ushort_t*)carve((size_t)3 * 16384 * 2);  // swizzled bf16 W
  (void)n_in;
  (void)ws_size;

  hipMemsetAsync(pooled, 0, (size_t)G * FDIM * 4, stream);

  k_histw<<<NCH + 3, 256, 0, stream>>>(dst, E, NB, chunkHist, NCH, W1, W2, W3, wsw);
  k_scan1<<<NB, 512, 0, stream>>>(chunkHist, NCH, NB, chunkOff, bucketTotal);
  k_scan2<<<1, 512, 0, stream>>>(bucketTotal, NB, E, bucketBase);
  k_bin<<<NCH, 256, 0, stream>>>(src, dst, E, NB, chunkHist, chunkOff, bucketBase,
                                 binned);
  k_fill2<<<NB, 256, 0, stream>>>(binned, bucketBase, N, rowStart, deg, dis, colPair);

  int mmb = (N + 127) / 128;
  int ewb = (E + 2047) / 2048;
  int aggb = (N + 7) / 8;
  k_mm<0, 1><<<mmb + ewb, 256, 0, stream>>>(x, wsw, h0, N, mmb, colPair, E, dis);
  k_agg<<<aggb, 256, 0, stream>>>(h0, h1, rowStart, deg, colPair, dis, b1, N);
  k_mm<1, 0><<<mmb, 256, 0, stream>>>(h1, wsw + 16384, h0, N, mmb, nullptr, 0, nullptr);
  k_agg<<<aggb, 256, 0, stream>>>(h0, h1, rowStart, deg, colPair, dis, b2, N);
  k_mm<1, 0><<<mmb, 256, 0, stream>>>(h1, wsw + 32768, h0, N, mmb, nullptr, 0, nullptr);
  k_agg<<<aggb, 256, 0, stream>>>(h0, h1, rowStart, deg, colPair, dis, b3, N);

  k_gstart<<<1, 128, 0, stream>>>(batch, N, G, gstart);
  k_pool<<<G * 16, 128, 0, stream>>>(h1, gstart, pooled, G);
  k_final<<<1, 192, 0, stream>>>(pooled, gstart, Wc, bc, out, G);
}

// Round 12
// 426.404 us; speedup vs baseline: 1.2272x; 1.0122x over previous
//
#include <hip/hip_runtime.h>
#include <cstdint>
#include <cstddef>

#define FDIM 128
#define CHUNK 4096   // edges per binning chunk
#define BSHIFT 8     // 256 nodes per bucket
#define BMASK 255
#define MAXB 512     // max buckets supported (N <= 131072)

typedef unsigned short ushort_t;
typedef __attribute__((ext_vector_type(8))) short short8;   // 8 bf16 (4 VGPRs)
typedef __attribute__((ext_vector_type(4))) float floatx4;  // MFMA C/D

// bf16 helpers (bit-level, RTN-even).
__device__ inline ushort_t f2bf(float f) {
  unsigned u = __float_as_uint(f);
  u += 0x7fffu + ((u >> 16) & 1u);
  return (ushort_t)(u >> 16);
}
__device__ inline float bf2f(ushort_t h) {
  return __uint_as_float((unsigned)h << 16);
}

// ---------------- CSR build (bucketed) ----------------
// k_histw: blocks [0,NCH) = per-chunk dst-bucket histogram; blocks
// [NCH,NCH+3) = W prep (fused). Block NCH also zeroes the bump counter.
__global__ __launch_bounds__(256) void k_histw(const int* __restrict__ dst, int e,
                                               int nb, int* __restrict__ chunkHist,
                                               int nch,
                                               const float* __restrict__ W1,
                                               const float* __restrict__ W2,
                                               const float* __restrict__ W3,
                                               ushort_t* __restrict__ wsw,
                                               int* __restrict__ counter) {
  if (blockIdx.x >= (unsigned)nch) {
    int b = blockIdx.x - nch;
    if (b == 0 && threadIdx.x == 0) *counter = 0;  // for scan1's atomic bump
    // W prep: fp32 -> bf16, B-fragment order. Frag slot (ct, n=lane&15)
    // holds TRUE column (lane&15)*8+ct -> coalesced uint4 C-stores in k_mm.
    const float* W = (b == 0) ? W1 : (b == 1) ? W2 : W3;
    ushort_t* o = wsw + (size_t)b * 16384;
    for (int idx = threadIdx.x; idx < 16384; idx += 256) {
      int j = idx & 7;
      int lane = (idx >> 3) & 63;
      int ct = (idx >> 9) & 7;
      int kc = idx >> 12;
      int k = kc * 32 + (lane >> 4) * 8 + j;
      int col = (lane & 15) * 8 + ct;
      o[idx] = f2bf(W[k * FDIM + col]);
    }
    return;
  }
  __shared__ int h[MAXB];
  int c = blockIdx.x;
  int base = c * CHUNK;
  int end = min(base + CHUNK, e);
  for (int i = threadIdx.x; i < nb; i += 256) h[i] = 0;
  __syncthreads();
  for (int i = base + threadIdx.x; i < end; i += 256)
    atomicAdd(&h[dst[i] >> BSHIFT], 1);
  __syncthreads();
  for (int b = threadIdx.x; b < nb; b += 256)
    chunkHist[(size_t)c * nb + b] = h[b];
}

// Per-bucket scan over the chunk axis; bucket base atomic-bump allocated
// (disjoint segments, order-free -- validated R10; kills k_scan2).
__global__ __launch_bounds__(512) void k_scan1(const int* __restrict__ chunkHist,
                                               int nchunks, int nb,
                                               int* __restrict__ chunkOff,
                                               int* __restrict__ bucketTotal,
                                               int* __restrict__ bucketBase,
                                               int* __restrict__ counter) {
  __shared__ int sb[512];
  int b = blockIdx.x;
  int t = threadIdx.x;
  int base = 0;
  for (int c0 = 0; c0 < nchunks; c0 += 512) {
    int c = c0 + t;
    int v = (c < nchunks) ? chunkHist[(size_t)c * nb + b] : 0;
    int x = v;
    sb[t] = x;
    __syncthreads();
    for (int off = 1; off < 512; off <<= 1) {
      int y = (t >= off) ? sb[t - off] : 0;
      __syncthreads();
      x += y;
      sb[t] = x;
      __syncthreads();
    }
    if (c < nchunks) chunkOff[(size_t)c * nb + b] = base + x - v;
    int tileTot = sb[511];
    __syncthreads();
    base += tileTot;
  }
  if (t == 0) {
    bucketTotal[b] = base;
    bucketBase[b] = atomicAdd(counter, base);
  }
}

__global__ __launch_bounds__(256) void k_bin(const int* __restrict__ src,
                                             const int* __restrict__ dst, int e, int nb,
                                             const int* __restrict__ chunkHist,
                                             const int* __restrict__ chunkOff,
                                             const int* __restrict__ bucketBase,
                                             unsigned* __restrict__ binned) {
  __shared__ unsigned sortedL[CHUNK];
  __shared__ int gtarget[CHUNK];
  __shared__ int lbase[MAXB], lcur[MAXB], gbase[MAXB];
  __shared__ int stmp[256];
  int c = blockIdx.x;
  int base = c * CHUNK;
  int end = min(base + CHUNK, e);
  for (int i = threadIdx.x; i < nb; i += 256) {
    lbase[i] = chunkHist[(size_t)c * nb + i];  // temp: counts
    gbase[i] = bucketBase[i] + chunkOff[(size_t)c * nb + i];
  }
  __syncthreads();
  int carry = 0;
  for (int i0 = 0; i0 < nb; i0 += 256) {
    int i = i0 + threadIdx.x;
    int v = (i < nb) ? lbase[i] : 0;
    int x = v;
    stmp[threadIdx.x] = x;
    __syncthreads();
    for (int off = 1; off < 256; off <<= 1) {
      int y = (threadIdx.x >= off) ? stmp[threadIdx.x - off] : 0;
      __syncthreads();
      x += y;
      stmp[threadIdx.x] = x;
      __syncthreads();
    }
    if (i < nb) lbase[i] = carry + x - v;
    int tileTot = stmp[255];
    __syncthreads();
    carry += tileTot;
  }
  for (int i = threadIdx.x; i < nb; i += 256) lcur[i] = lbase[i];
  __syncthreads();
  for (int i = base + threadIdx.x; i < end; i += 256) {
    int d = dst[i];
    int sv = src[i];
    int b = d >> BSHIFT;
    int slot = atomicAdd(&lcur[b], 1);
    sortedL[slot] = ((unsigned)sv << BSHIFT) | (unsigned)(d & BMASK);
    gtarget[slot] = gbase[b] + (slot - lbase[b]);
  }
  __syncthreads();
  for (int i = threadIdx.x; i < end - base; i += 256)
    binned[gtarget[i]] = sortedL[i];
}

// One block per bucket: per-node CSR rows in the bucket's private window.
// colPacked written as src only; the fused edgew pass ORs in the bf15 weight.
__global__ __launch_bounds__(256) void k_fill2(const unsigned* __restrict__ binned,
                                               const int* __restrict__ bucketBase,
                                               const int* __restrict__ bucketTotal,
                                               int n,
                                               int* __restrict__ rowStart,
                                               int* __restrict__ deg,
                                               float* __restrict__ dis,
                                               unsigned* __restrict__ colPacked) {
  __shared__ int h[256], sb[256], cur[256];
  int b = blockIdx.x;
  int s0 = bucketBase[b], s1 = s0 + bucketTotal[b];
  int nodeBase = b << BSHIFT;
  int t = threadIdx.x;
  h[t] = 0;
  __syncthreads();
  for (int i = s0 + t; i < s1; i += 256) atomicAdd(&h[binned[i] & BMASK], 1);
  __syncthreads();
  int v = h[t];
  int x = v;
  sb[t] = x;
  __syncthreads();
  for (int off = 1; off < 256; off <<= 1) {
    int y = (t >= off) ? sb[t - off] : 0;
    __syncthreads();
    x += y;
    sb[t] = x;
    __syncthreads();
  }
  int start = s0 + x - v;
  cur[t] = start;
  int node = nodeBase + t;
  if (node < n) {
    rowStart[node] = start;
    deg[node] = v;
    dis[node] = rsqrtf((float)(v + 1));  // +1 self-loop
  }
  __syncthreads();
  for (int i = s0 + t; i < s1; i += 256) {
    unsigned en = binned[i];
    int slot = atomicAdd(&cur[en & BMASK], 1);
    colPacked[slot] = en >> BSHIFT;  // src (< 2^17); weight ORed in later
  }
}

// ---------------- MFMA matmul (row-major H) ----------
// Blocks [0,mmb) = matmul; blocks [mmb,..) (EDGW=1 only, first layer) pack
// the edge weight: colPacked[i] |= bf16(dis[src])<<17 (dis positive -> sign
// bit free; 15-bit weight + 17-bit src in 4 B -- halves the agg edge stream).
template <int INBF, int EDGW>
__global__ __launch_bounds__(256) void k_mm(const void* __restrict__ Ain,
                                            const ushort_t* __restrict__ Wsw,
                                            ushort_t* __restrict__ O, int n, int mmb,
                                            unsigned* __restrict__ colPacked, int e,
                                            const float* __restrict__ dis) {
  if (EDGW && blockIdx.x >= (unsigned)mmb) {
    int base = (blockIdx.x - mmb) * 2048 + threadIdx.x;
    for (int k = 0; k < 8; ++k) {
      int i = base + k * 256;
      if (i < e) {
        unsigned p = colPacked[i];  // pure src here
        colPacked[i] = p | ((unsigned)f2bf(dis[p]) << 17);
      }
    }
    return;
  }
  __shared__ ushort_t Bs[16384];  // 32 KB
  int tid = threadIdx.x;
  for (int q = tid; q < 2048; q += 256)
    ((uint4*)Bs)[q] = ((const uint4*)Wsw)[q];
  __syncthreads();

  int w = tid >> 6;
  int lane = tid & 63;
  int quad = lane >> 4;
  int l15 = lane & 15;
  int rb = blockIdx.x * 128 + w * 32;
  const float* Af = (const float*)Ain;
  const ushort_t* Ab = (const ushort_t*)Ain;

  int row0 = rb + l15;
  int row1 = rb + 16 + l15;
  bool v0 = row0 < n, v1 = row1 < n;

  floatx4 acc[2][8];
#pragma unroll
  for (int rt = 0; rt < 2; ++rt)
#pragma unroll
    for (int ct = 0; ct < 8; ++ct) acc[rt][ct] = floatx4{0.f, 0.f, 0.f, 0.f};

#pragma unroll
  for (int kc = 0; kc < 4; ++kc) {
    int k0 = kc * 32 + quad * 8;
    short8 a0 = short8{0, 0, 0, 0, 0, 0, 0, 0};
    short8 a1 = short8{0, 0, 0, 0, 0, 0, 0, 0};
    if (INBF) {
      if (v0) a0 = *(const short8*)&Ab[(size_t)row0 * FDIM + k0];
      if (v1) a1 = *(const short8*)&Ab[(size_t)row1 * FDIM + k0];
    } else {
      if (v0) {
        float4 f0 = *(const float4*)&Af[(size_t)row0 * FDIM + k0];
        float4 f1 = *(const float4*)&Af[(size_t)row0 * FDIM + k0 + 4];
        a0 = short8{(short)f2bf(f0.x), (short)f2bf(f0.y), (short)f2bf(f0.z),
                    (short)f2bf(f0.w), (short)f2bf(f1.x), (short)f2bf(f1.y),
                    (short)f2bf(f1.z), (short)f2bf(f1.w)};
      }
      if (v1) {
        float4 f0 = *(const float4*)&Af[(size_t)row1 * FDIM + k0];
        float4 f1 = *(const float4*)&Af[(size_t)row1 * FDIM + k0 + 4];
        a1 = short8{(short)f2bf(f0.x), (short)f2bf(f0.y), (short)f2bf(f0.z),
                    (short)f2bf(f0.w), (short)f2bf(f1.x), (short)f2bf(f1.y),
                    (short)f2bf(f1.z), (short)f2bf(f1.w)};
      }
    }
#pragma unroll
    for (int ct = 0; ct < 8; ++ct) {
      short8 bf = *(const short8*)&Bs[((kc * 8 + ct) * 64 + lane) * 8];
      acc[0][ct] = __builtin_amdgcn_mfma_f32_16x16x32_bf16(a0, bf, acc[0][ct], 0, 0, 0);
      acc[1][ct] = __builtin_amdgcn_mfma_f32_16x16x32_bf16(a1, bf, acc[1][ct], 0, 0, 0);
    }
  }

#pragma unroll
  for (int rt = 0; rt < 2; ++rt) {
#pragma unroll
    for (int i = 0; i < 4; ++i) {
      int row = rb + rt * 16 + quad * 4 + i;
      if (row < n) {
        uint4 pk;
        pk.x = (unsigned)f2bf(acc[rt][0][i]) | ((unsigned)f2bf(acc[rt][1][i]) << 16);
        pk.y = (unsigned)f2bf(acc[rt][2][i]) | ((unsigned)f2bf(acc[rt][3][i]) << 16);
        pk.z = (unsigned)f2bf(acc[rt][4][i]) | ((unsigned)f2bf(acc[rt][5][i]) << 16);
        pk.w = (unsigned)f2bf(acc[rt][6][i]) | ((unsigned)f2bf(acc[rt][7][i]) << 16);
        *(uint4*)&O[(size_t)row * FDIM + l15 * 8] = pk;
      }
    }
  }
}

// ---------------- aggregation (pull) + bias + ReLU ------------------------
// 2 nodes per wave: 32 lanes x uint2 (8 B) = 256 B row. colPacked: one 4 B
// broadcast load per edge (was 8 B). Cached loads (nt regressed, R10).
__global__ __launch_bounds__(256) void k_agg(const ushort_t* __restrict__ Hin,
                                             ushort_t* __restrict__ Hout,
                                             const int* __restrict__ rowStart,
                                             const int* __restrict__ degE,
                                             const unsigned* __restrict__ colPacked,
                                             const float* __restrict__ dis,
                                             const float* __restrict__ bias, int n) {
  int node = blockIdx.x * 8 + (threadIdx.x >> 5);
  int lane = threadIdx.x & 31;  // uint2 index within the 256 B row
  if (node >= n) return;
  const uint2* hin = (const uint2*)Hin;  // row stride 32 uint2
  float di = dis[node];
  uint2 su = hin[(size_t)node * 32 + lane];
  float ws = di * di;
  float a0 = ws * __uint_as_float(su.x << 16);
  float a1 = ws * __uint_as_float(su.x & 0xffff0000u);
  float a2 = ws * __uint_as_float(su.y << 16);
  float a3 = ws * __uint_as_float(su.y & 0xffff0000u);
  int s0 = rowStart[node], cnt = degE[node];
#pragma unroll 4
  for (int j = 0; j < cnt; ++j) {
    unsigned pv = colPacked[s0 + j];
    int sidx = (int)(pv & 0x1ffffu);
    float w = di * __uint_as_float((pv >> 17) << 16);
    uint2 u = hin[(size_t)sidx * 32 + lane];
    a0 += w * __uint_as_float(u.x << 16);
    a1 += w * __uint_as_float(u.x & 0xffff0000u);
    a2 += w * __uint_as_float(u.y << 16);
    a3 += w * __uint_as_float(u.y & 0xffff0000u);
  }
  float4 b = ((const float4*)bias)[lane];
  a0 = fmaxf(a0 + b.x, 0.f);
  a1 = fmaxf(a1 + b.y, 0.f);
  a2 = fmaxf(a2 + b.z, 0.f);
  a3 = fmaxf(a3 + b.w, 0.f);
  uint2 o;
  o.x = (unsigned)f2bf(a0) | ((unsigned)f2bf(a1) << 16);
  o.y = (unsigned)f2bf(a2) | ((unsigned)f2bf(a3) << 16);
  ((uint2*)Hout)[(size_t)node * 32 + lane] = o;
}

// ---------------- pooling (partials, no atomics/memset) -------------------

__device__ inline int lower_bound_batch(const int* __restrict__ batch, int n, int g) {
  int lo = 0, hi = n;
  while (lo < hi) {
    int mid = (lo + hi) >> 1;
    if (batch[mid] < g) lo = mid + 1;
    else hi = mid;
  }
  return lo;
}

__global__ __launch_bounds__(128) void k_pool(const ushort_t* __restrict__ H,
                                              const int* __restrict__ batch, int n,
                                              float* __restrict__ partials,
                                              int g_count) {
  __shared__ int se[2];
  int g = blockIdx.x >> 4;
  int c = blockIdx.x & 15;
  if (threadIdx.x < 2)
    se[threadIdx.x] = lower_bound_batch(batch, n, g + (int)threadIdx.x);
  __syncthreads();
  int s = se[0], e = se[1];
  int chunk = (e - s + 15) >> 4;
  int ns = s + c * chunk;
  int ne = min(ns + chunk, e);
  float acc = 0.f;
  for (int i = ns; i < ne; ++i) acc += bf2f(H[(size_t)i * FDIM + threadIdx.x]);
  partials[((size_t)g * 16 + c) * FDIM + threadIdx.x] = acc;  // always written
}

// One block per graph: reduce 16 partials, classify via wave shuffles.
__global__ __launch_bounds__(128) void k_final(const float* __restrict__ partials,
                                               const int* __restrict__ batch, int n,
                                               const float* __restrict__ Wc,
                                               const float* __restrict__ bc,
                                               float* __restrict__ out, int g_count) {
  __shared__ int se[2];
  __shared__ float red[6];  // 2 waves x 3 classes
  int t = threadIdx.x;
  int g = blockIdx.x;
  if (t < 2) se[t] = lower_bound_batch(batch, n, g + t);
  __syncthreads();
  float inv = 1.0f / (float)max(se[1] - se[0], 1);
  float s = 0.f;
#pragma unroll
  for (int p = 0; p < 16; ++p) s += partials[((size_t)g * 16 + p) * FDIM + t];
  s *= inv;
#pragma unroll
  for (int c = 0; c < 3; ++c) {
    float v = s * Wc[t * 3 + c];
#pragma unroll
    for (int off = 1; off < 64; off <<= 1) v += __shfl_xor(v, off);
    if ((t & 63) == 0) red[(t >> 6) * 3 + c] = v;
  }
  __syncthreads();
  if (t < 3) out[g * 3 + t] = red[t] + red[3 + t] + bc[t];
}

// ---------------- host ----------------

extern "C" void kernel_launch(void* const* d_in, const int* in_sizes, int n_in,
                              void* d_out, int out_size, void* d_ws, size_t ws_size,
                              hipStream_t stream) {
  const float* x = (const float*)d_in[0];
  const int* edge = (const int*)d_in[1];
  const int* batch = (const int*)d_in[2];
  const float* W1 = (const float*)d_in[3];
  const float* b1 = (const float*)d_in[4];
  const float* W2 = (const float*)d_in[5];
  const float* b2 = (const float*)d_in[6];
  const float* W3 = (const float*)d_in[7];
  const float* b3 = (const float*)d_in[8];
  const float* Wc = (const float*)d_in[9];
  const float* bc = (const float*)d_in[10];
  float* out = (float*)d_out;

  const int N = in_sizes[0] / FDIM;
  const int E = in_sizes[1] / 2;
  const int G = out_size / 3;
  const int* src = edge;
  const int* dst = edge + E;

  const int NCH = (E + CHUNK - 1) / CHUNK;
  const int NB = (N + (1 << BSHIFT) - 1) >> BSHIFT;

  char* ws = (char*)d_ws;
  size_t off = 0;
  auto carve = [&](size_t bytes) -> void* {
    void* p = ws + off;
    off = (off + bytes + 255) & ~(size_t)255;
    return p;
  };
  ushort_t* h0 = (ushort_t*)carve((size_t)N * FDIM * 2);  // row-major bf16
  ushort_t* h1 = (ushort_t*)carve((size_t)N * FDIM * 2);
  unsigned* colPacked = (unsigned*)carve((size_t)E * 4);
  unsigned* binned = (unsigned*)carve((size_t)E * 4);
  int* chunkHist = (int*)carve((size_t)NCH * NB * 4);
  int* chunkOff = (int*)carve((size_t)NCH * NB * 4);
  int* bucketTotal = (int*)carve((size_t)NB * 4);
  int* bucketBase = (int*)carve((size_t)NB * 4);
  int* counter = (int*)carve(256);
  int* rowStart = (int*)carve((size_t)N * 4);
  int* deg = (int*)carve((size_t)N * 4);
  float* dis = (float*)carve((size_t)N * 4);
  float* partials = (float*)carve((size_t)G * 16 * FDIM * 4);
  ushort_t* wsw = (ushort_t*)carve((size_t)3 * 16384 * 2);  // swizzled bf16 W
  (void)n_in;
  (void)ws_size;

  k_histw<<<NCH + 3, 256, 0, stream>>>(dst, E, NB, chunkHist, NCH, W1, W2, W3, wsw,
                                       counter);
  k_scan1<<<NB, 512, 0, stream>>>(chunkHist, NCH, NB, chunkOff, bucketTotal,
                                  bucketBase, counter);
  k_bin<<<NCH, 256, 0, stream>>>(src, dst, E, NB, chunkHist, chunkOff, bucketBase,
                                 binned);
  k_fill2<<<NB, 256, 0, stream>>>(binned, bucketBase, bucketTotal, N, rowStart, deg,
                                  dis, colPacked);

  int mmb = (N + 127) / 128;
  int ewb = (E + 2047) / 2048;
  int aggb = (N + 7) / 8;
  k_mm<0, 1><<<mmb + ewb, 256, 0, stream>>>(x, wsw, h0, N, mmb, colPacked, E, dis);
  k_agg<<<aggb, 256, 0, stream>>>(h0, h1, rowStart, deg, colPacked, dis, b1, N);
  k_mm<1, 0><<<mmb, 256, 0, stream>>>(h1, wsw + 16384, h0, N, mmb, nullptr, 0,
                                      nullptr);
  k_agg<<<aggb, 256, 0, stream>>>(h0, h1, rowStart, deg, colPacked, dis, b2, N);
  k_mm<1, 0><<<mmb, 256, 0, stream>>>(h1, wsw + 32768, h0, N, mmb, nullptr, 0,
                                      nullptr);
  k_agg<<<aggb, 256, 0, stream>>>(h0, h1, rowStart, deg, colPacked, dis, b3, N);

  k_pool<<<G * 16, 128, 0, stream>>>(h1, batch, N, partials, G);
  k_final<<<G, 128, 0, stream>>>(partials, batch, N, Wc, bc, out, G);
}